// Round 9
// baseline (249.064 us; speedup 1.0000x reference)
//
#include <hip/hip_runtime.h>

// out[m,n] = Sx*Sy * ( dot_i8[m,n] - ZPy*rowsumX[m] - ZPx*colsumY[n] + K*ZPx*ZPy )
// ZP_X=-25, ZP_Y=18, K=4096  ->  const term = 4096*(-25)*18 = -1843200

typedef int v4i  __attribute__((ext_vector_type(4)));
typedef int v16i __attribute__((ext_vector_type(16)));

#define MDIM 4096
#define KDIM 4096
#define NDIM 4096

__device__ __forceinline__ void gload_lds16(const void* g, void* l) {
    __builtin_amdgcn_global_load_lds((const __attribute__((address_space(1))) void*)g,
                                     (__attribute__((address_space(3))) void*)l, 16, 0, 0);
}

__device__ __forceinline__ int pack4(int a, int b, int c, int d) {
    return (a & 255) | ((b & 255) << 8) | ((c & 255) << 16) | ((d & 255) << 24);
}

// ---------------------------------------------------------------------------
// Pack X (int32 -> int8) into fragment-ordered tiles + rowsum. (unchanged)
// ---------------------------------------------------------------------------
__global__ __launch_bounds__(256) void pack_a(const int* __restrict__ x,
                                              signed char* __restrict__ pA,
                                              int* __restrict__ rsX) {
    int o = blockIdx.x * 256 + threadIdx.x;      // [0, 1M)
    int frag = o & 511;
    int tileIdx = o >> 9;
    int r = frag & 15;
    int kg = (frag >> 4) & 3;
    int mf = frag >> 6;
    int mtile = tileIdx >> 6, ktile = tileIdx & 63;
    int row = mtile * 128 + mf * 16 + r;
    int k0 = ktile * 64 + kg * 16;

    const int4* src = (const int4*)(x + (size_t)row * KDIM + k0);
    int out[4];
    int s = 0;
    #pragma unroll
    for (int i = 0; i < 4; ++i) {
        int4 v = src[i];
        out[i] = pack4(v.x, v.y, v.z, v.w);
        s += v.x + v.y + v.z + v.w;
    }
    *(int4*)(pA + (size_t)o * 16) = *(const int4*)out;

    s += __shfl_xor(s, 16, 64);
    s += __shfl_xor(s, 32, 64);
    if ((threadIdx.x & 63) < 16) atomicAdd(&rsX[row], s);
}

// ---------------------------------------------------------------------------
// Pack Y (int32 -> int8) with transpose, in registers. (unchanged)
// ---------------------------------------------------------------------------
__global__ __launch_bounds__(256) void pack_b(const int* __restrict__ y,
                                              signed char* __restrict__ pB) {
    int o = blockIdx.x * 256 + threadIdx.x;      // [0, 1M)
    int frag = o & 511;
    int tileIdx = o >> 9;
    int c = frag & 15;
    int kg = (frag >> 4) & 3;
    int nf = frag >> 6;
    int ntile = tileIdx >> 6, ktile = tileIdx & 63;
    int n = ntile * 128 + nf * 16 + c;
    int k0 = ktile * 64 + kg * 16;

    const int* src = y + (size_t)k0 * NDIM + n;
    int out[4];
    #pragma unroll
    for (int g = 0; g < 4; ++g) {
        int b0 = src[(size_t)(g * 4 + 0) * NDIM];
        int b1 = src[(size_t)(g * 4 + 1) * NDIM];
        int b2 = src[(size_t)(g * 4 + 2) * NDIM];
        int b3 = src[(size_t)(g * 4 + 3) * NDIM];
        out[g] = pack4(b0, b1, b2, b3);
    }
    *(int4*)(pB + (size_t)o * 16) = *(const int4*)out;
}

// ---------------------------------------------------------------------------
// Column sums of y from packed B. (unchanged)
// ---------------------------------------------------------------------------
__device__ __forceinline__ int sbsum(int v) {
    return ((v << 24) >> 24) + ((v << 16) >> 24) + ((v << 8) >> 24) + (v >> 24);
}

__global__ __launch_bounds__(256) void colsum_b(const signed char* __restrict__ pB,
                                                int* __restrict__ csY) {
    int ntile = blockIdx.x >> 2;
    int kc = blockIdx.x & 3;
    int tid = threadIdx.x;
    int nl = tid & 127;
    int kgh = tid >> 7;
    int nf = nl >> 4, c = nl & 15;
    int sum = 0;
    for (int kt = 0; kt < 16; ++kt) {
        size_t tbase = (size_t)(ntile * 64 + kc * 16 + kt) * 8192;
        #pragma unroll
        for (int g = 0; g < 2; ++g) {
            int kg = kgh * 2 + g;
            v4i v = *(const v4i*)(pB + tbase + (size_t)(((nf * 4 + kg) * 16 + c) * 16));
            sum += sbsum(v.x) + sbsum(v.y) + sbsum(v.z) + sbsum(v.w);
        }
    }
    atomicAdd(&csY[ntile * 128 + nl], sum);
}

// ---------------------------------------------------------------------------
// i8 MFMA GEMM, 256x256 tile, 8 waves (2x4), BK=128, 32x32x32 MFMA.
// Round-9: r8's 2-barrier + counted-vmcnt skeleton, plus T19
// sched_group_barrier interleave: 4 rotating register sets (S0..S3, one per
// k-step), iter body emitted as {DS6} 8x{MFMA1,DS1} 8x{MFMA1,DS1}
// 2x{MFMA1,DS1}+6x{MFMA1} {MFMA8} — LDS-read pipe (2304 cyc/CU/iter) runs
// UNDER the MFMA pipe (2340 cyc) instead of serially after it (r8 counters:
// serial sum == measured duration).
// ---------------------------------------------------------------------------
__global__ __launch_bounds__(512, 2) void gemm_i8(const signed char* __restrict__ pA,
                                                  const signed char* __restrict__ pB,
                                                  const int* __restrict__ rsX,
                                                  const int* __restrict__ csY,
                                                  float* __restrict__ out) {
    __shared__ __align__(16) signed char lds[131072];
    signed char* ldsA = lds;            // [buf][h][2 x 8192B sub-tiles]
    signed char* ldsB = lds + 65536;

    const int bn = blockIdx.x, bm = blockIdx.y;
    const int tid = threadIdx.x;
    const int w = tid >> 6, lane = tid & 63;
    const int wr = w >> 2;               // 0..1 : A half (128 rows)
    const int wc = w & 3;                // 0..3 : 64-col slice
    const int hb = wc >> 1;              // B half
    const int nfb = (wc & 1) * 4;        // nf16 base within B half
    const int t16 = tid * 16;

    // per-lane offset inside a 32-row fragment (row = lane&31, k-parity = lane>>5)
    const int foff = ((lane >> 4) & 1) * 1024 + (lane >> 5) * 256 + (lane & 15) * 16;

    v16i acc[4][2] = {};

    // prologue: stage K-tile 0 into buf 0
    #pragma unroll
    for (int h = 0; h < 2; ++h) {
        const signed char* sa = pA + ((size_t)((2 * bm + h) * 64)) * 8192 + t16;
        signed char* da = ldsA + h * 16384 + t16;
        gload_lds16(sa, da);
        gload_lds16(sa + 8192, da + 8192);
        const signed char* sb = pB + ((size_t)((2 * bn + h) * 64)) * 8192 + t16;
        signed char* db = ldsB + h * 16384 + t16;
        gload_lds16(sb, db);
        gload_lds16(sb + 8192, db + 8192);
    }

#define STAGE_A(H) do {                                                          \
        const signed char* s_ = pA + ((size_t)((2 * bm + (H)) * 64 + 2 * tn)) * 8192 + t16; \
        signed char* d_ = ldsA + nxt * 32768 + (H) * 16384 + t16;                \
        gload_lds16(s_, d_);                                                     \
        gload_lds16(s_ + 8192, d_ + 8192);                                       \
    } while (0)

#define STAGE_B(H) do {                                                          \
        const signed char* s_ = pB + ((size_t)((2 * bn + (H)) * 64 + 2 * tn)) * 8192 + t16; \
        signed char* d_ = ldsB + nxt * 32768 + (H) * 16384 + t16;                \
        gload_lds16(s_, d_);                                                     \
        gload_lds16(s_ + 8192, d_ + 8192);                                       \
    } while (0)

// four rotating register sets: S in {0,1,2,3}; k-step byte offsets
// 0, 512 (sub-tile 0) and 8192, 8704 (sub-tile 1)
#define READS(S, KOFS)                                                           \
    a##S##0 = *(const v4i*)(La + 0 * 2048 + (KOFS));                             \
    a##S##1 = *(const v4i*)(La + 1 * 2048 + (KOFS));                             \
    a##S##2 = *(const v4i*)(La + 2 * 2048 + (KOFS));                             \
    a##S##3 = *(const v4i*)(La + 3 * 2048 + (KOFS));                             \
    b##S##0 = *(const v4i*)(Lb + 0 * 2048 + (KOFS));                             \
    b##S##1 = *(const v4i*)(Lb + 1 * 2048 + (KOFS));

#define MFMA8(S)                                                                 \
    acc[0][0] = __builtin_amdgcn_mfma_i32_32x32x32_i8(a##S##0, b##S##0, acc[0][0], 0, 0, 0); \
    acc[1][0] = __builtin_amdgcn_mfma_i32_32x32x32_i8(a##S##1, b##S##0, acc[1][0], 0, 0, 0); \
    acc[2][0] = __builtin_amdgcn_mfma_i32_32x32x32_i8(a##S##2, b##S##0, acc[2][0], 0, 0, 0); \
    acc[3][0] = __builtin_amdgcn_mfma_i32_32x32x32_i8(a##S##3, b##S##0, acc[3][0], 0, 0, 0); \
    acc[0][1] = __builtin_amdgcn_mfma_i32_32x32x32_i8(a##S##0, b##S##1, acc[0][1], 0, 0, 0); \
    acc[1][1] = __builtin_amdgcn_mfma_i32_32x32x32_i8(a##S##1, b##S##1, acc[1][1], 0, 0, 0); \
    acc[2][1] = __builtin_amdgcn_mfma_i32_32x32x32_i8(a##S##2, b##S##1, acc[2][1], 0, 0, 0); \
    acc[3][1] = __builtin_amdgcn_mfma_i32_32x32x32_i8(a##S##3, b##S##1, acc[3][1], 0, 0, 0);

#define SGB(mask, n) __builtin_amdgcn_sched_group_barrier(mask, n, 0)
#define G_MFMA 0x8
#define G_DS   0x100

    v4i a00, a01, a02, a03, b00, b01;
    v4i a10, a11, a12, a13, b10, b11;
    v4i a20, a21, a22, a23, b20, b21;
    v4i a30, a31, a32, a33, b30, b31;

    for (int t = 0; t < KDIM / 128; ++t) {
        const int cur = t & 1, nxt = cur ^ 1;
        const int tn = (t < KDIM / 128 - 1) ? t + 1 : t;   // last iter: harmless re-stage
        const signed char* La = ldsA + cur * 32768 + wr * 16384 + foff;
        const signed char* Lb = ldsB + cur * 32768 + hb * 16384 + nfb * 1024 + foff;

        // barrier #1: all waves finished reading buffer `nxt` in iter t-1
        __builtin_amdgcn_s_barrier();
        __builtin_amdgcn_sched_barrier(0);

        // stage K-tile t+1 into nxt (8 global_load_lds)
        STAGE_A(0); STAGE_A(1); STAGE_B(0); STAGE_B(1);

        // my 8 loads from iter t-1 (into cur) are the oldest in flight
        asm volatile("s_waitcnt vmcnt(8)" ::: "memory");
        __builtin_amdgcn_sched_barrier(0);
        // barrier #2: everyone's cur-staging resident
        __builtin_amdgcn_s_barrier();
        __builtin_amdgcn_sched_barrier(0);

        // ---- SGB-pinned interleave over the whole iter body ----
        // instruction soup (program order): all reads + all MFMAs
        READS(0, 0)
        READS(1, 512)
        READS(2, 8192)
        READS(3, 8704)
        MFMA8(0)
        MFMA8(1)
        MFMA8(2)
        MFMA8(3)
        // emission pattern: S0 reads first, then MFMA stream with DS slipped in
        SGB(G_DS, 6);                       // S0 reads
        #pragma unroll
        for (int g = 0; g < 8; ++g) { SGB(G_MFMA, 1); SGB(G_DS, 1); }  // MF(S0) + S1(6)+S2(2)
        #pragma unroll
        for (int g = 0; g < 8; ++g) { SGB(G_MFMA, 1); SGB(G_DS, 1); }  // MF(S1) + S2(4)+S3(4)
        SGB(G_MFMA, 1); SGB(G_DS, 1);       // MF(S2) starts + S3(5)
        SGB(G_MFMA, 1); SGB(G_DS, 1);       //            + S3(6)
        SGB(G_MFMA, 6);                     // rest of MF(S2)
        SGB(G_MFMA, 8);                     // MF(S3)
        __builtin_amdgcn_sched_barrier(0);
    }

    // epilogue: out = S * (dot - 18*rsX[m] + 25*csY[n] - 1843200)
    // 32x32 C/D layout: col = lane&31, row = (reg&3) + 8*(reg>>2) + 4*(lane>>5)
    const float S = 0.0215f * 0.0176f;
    const int rbase = bm * 256 + wr * 128;
    const int cbase = bn * 256 + wc * 64;
    const int lrow = 4 * (lane >> 5);
    const int lcol = lane & 31;
    #pragma unroll
    for (int nj = 0; nj < 2; ++nj) {
        const int col = cbase + nj * 32 + lcol;
        const int csv = 25 * csY[col] - 1843200;
        #pragma unroll
        for (int mj = 0; mj < 4; ++mj) {
            #pragma unroll
            for (int reg = 0; reg < 16; ++reg) {
                const int row = rbase + mj * 32 + (reg & 3) + 8 * (reg >> 2) + lrow;
                const int tv = acc[mj][nj][reg] - 18 * rsX[row] + csv;
                out[(size_t)row * NDIM + col] = S * (float)tv;
            }
        }
    }
#undef STAGE_A
#undef STAGE_B
#undef READS
#undef MFMA8
#undef SGB
}

// ---------------------------------------------------------------------------
extern "C" void kernel_launch(void* const* d_in, const int* in_sizes, int n_in,
                              void* d_out, int out_size, void* d_ws, size_t ws_size,
                              hipStream_t stream) {
    const int* x = (const int*)d_in[0];
    const int* y = (const int*)d_in[1];
    float* out = (float*)d_out;

    signed char* pA = (signed char*)d_ws;                       // 16 MB
    signed char* pB = pA + (size_t)(16u << 20);                 // 16 MB
    int* rsX = (int*)((char*)d_ws + (size_t)(32u << 20));       // 4096 int
    int* csY = rsX + 4096;                                      // 4096 int

    hipMemsetAsync(rsX, 0, 2 * 4096 * sizeof(int), stream);
    pack_a<<<MDIM * KDIM / 16 / 256, 256, 0, stream>>>(x, pA, rsX);
    pack_b<<<KDIM * NDIM / 16 / 256, 256, 0, stream>>>(y, pB);
    colsum_b<<<128, 256, 0, stream>>>(pB, csY);
    gemm_i8<<<dim3(NDIM / 256, MDIM / 256), 512, 0, stream>>>(pA, pB, rsX, csY, out);
}